// Round 1
// 2726.525 us; speedup vs baseline: 1.0581x; 1.0581x over previous
//
#include <hip/hip_runtime.h>
#include <math.h>

#define BATCH 128
#define SEQN  512
#define XF    128
#define HF    256
#define BC    16    // batch tile per block (per group)
#define HC    8     // h tile per block
#define TCH   8     // time-chunk for phase A
#define NBLK  256
#define NTHR  256
#define NGRP  8     // batch groups
#define GSZ   32    // blocks per group (h tiles)

// ---- LDS layout (word offsets), total 37220 words = 148880 B (<160 KiB) ----
#define OFF_W    0        // W_h  [k=256][j=8][g=4]           (8192, persistent)
#define OFF_WX   8192     // W_x  [k=128][j=8][g=6]           (6144, persistent)
#define OFF_G    14336    // gates [t=8][g=6][b*8+j]          (6144)
#define OFF_X    20480    // union: A: x [k=128][bt swz]      (16384)
                          //        B: h [k=256][b swz]       (4096)
#define OFF_CM   36864    // cm [b*8+j]                        (128)
#define OFF_TV   36992    // t-values [b*8+t]                  (128)
#define OFF_COEF 37120    // 12 coef vectors x 8               (96)
#define OFF_GO   37216    // LDS "go" counter for non-poll waves
#define LDS_WORDS 37220
#define LDS_BYTES (LDS_WORDS * 4)

struct Params {
  const float* x;
  const float* t;
  const float* w_h[4];   // fg, ig, in, og   [H][H]
  const float* w_x[6];   // fg, ig, in, og, tg1, tg2  [H][X]
  const float* coef[12]; // fg_b, ig_b, in_b, og_b, og_w_t, tg1_w_t, tg1_b, tg2_w_t, tg2_b, fg_w_c, ig_w_c, og_w_cn
  float* h_buf;          // ws: [2][H][B]  (transposed; all access agent-scope)
  unsigned* flags;       // ws: [NGRP][GSZ][16]  (cacheline-padded arrival slots)
  float* out;
};

__device__ __forceinline__ float sigmoidf_(float v) { return 1.0f / (1.0f + __expf(-v)); }

// in-wave lane exchange over kh = lane&7 (BitMode ds_swizzle: xor<<10 | and 0x1F)
__device__ __forceinline__ float swzx1(float v) { return __int_as_float(__builtin_amdgcn_ds_swizzle(__float_as_int(v), 0x041F)); }
__device__ __forceinline__ float swzx2(float v) { return __int_as_float(__builtin_amdgcn_ds_swizzle(__float_as_int(v), 0x081F)); }
__device__ __forceinline__ float swzx4(float v) { return __int_as_float(__builtin_amdgcn_ds_swizzle(__float_as_int(v), 0x101F)); }

// ---- fence-free point-to-point sync --------------------------------------
// Cross-block data (h_buf) moves via relaxed AGENT-scope atomics (coherence
// point). Release: __syncthreads() drains each wave's vmcnt(0) before
// s_barrier, so every h-store has landed before tid0 posts the flag.
// Acquire: wave0 polls flags, then either (a) proceeds (its own loads are
// issued after the poll-exit branch), or (b) other waves observe the LDS
// "go" counter wave0 bumps; their agent loads read the coherence point.
__device__ __forceinline__ void post_arrive(unsigned* flags, int gi, int mi, unsigned step) {
  __syncthreads();  // exec barrier + per-wave vmcnt(0) drain of agent h-stores
  if (threadIdx.x == 0) {
    __hip_atomic_store(&flags[(gi * GSZ + mi) * 16], step,
                       __ATOMIC_RELAXED, __HIP_MEMORY_SCOPE_AGENT);
  }
}

__device__ __forceinline__ void wave_wait(float* sm, const unsigned* flags,
                                          int gi, int mi, unsigned step) {
  unsigned* go = (unsigned*)&sm[OFF_GO];
  const int tid = threadIdx.x;
  if (tid < 64) {                       // wave 0: poll the 32 peer flags
    const bool need = (tid < GSZ) && (tid != mi);
    const unsigned* f = &flags[(gi * GSZ + (tid & (GSZ - 1))) * 16];
    while (true) {
      unsigned v = need ? __hip_atomic_load(f, __ATOMIC_RELAXED, __HIP_MEMORY_SCOPE_AGENT)
                        : step;
      if (__all((int)(v >= step))) break;
    }
    if (tid == 0)
      __hip_atomic_store(go, step, __ATOMIC_RELAXED, __HIP_MEMORY_SCOPE_WORKGROUP);
  } else {                              // waves 1-3: cheap LDS spin, no fabric traffic
    while (__hip_atomic_load(go, __ATOMIC_RELAXED, __HIP_MEMORY_SCOPE_WORKGROUP) < step) {}
  }
}

__global__ __launch_bounds__(NTHR, 1) void timelstm_kernel(Params p) {
  extern __shared__ float sm[];
  const int tid = threadIdx.x;
  const int bid = blockIdx.x;
  const int gi = bid & 7;          // batch group (XCD-resident under round-robin)
  const int mi = bid >> 3;         // member = h tile
  const int b0 = gi * BC;
  const int h0 = mi * HC;

  // ---- one-time: persistent weight slabs -> LDS ----
  for (int i = tid; i < 4 * 8 * 256; i += NTHR) {     // W_h: [k][j][g]
    int g = i >> 11, j = (i >> 8) & 7, k = i & 255;
    sm[OFF_W + k * 32 + j * 4 + g] = p.w_h[g][(h0 + j) * HF + k];
  }
  for (int i = tid; i < 6 * 8 * 128; i += NTHR) {     // W_x: [k][j][g]
    int g = i >> 10, j = (i >> 7) & 7, k = i & 127;
    sm[OFF_WX + k * 48 + j * 6 + g] = p.w_x[g][(h0 + j) * XF + k];
  }
  if (tid < 96) sm[OFF_COEF + tid] = p.coef[tid >> 3][h0 + (tid & 7)];
  if (tid < 128) sm[OFF_CM + tid] = 0.0f;             // cm[b*8+j] = 0
  if (tid == 0) *(unsigned*)&sm[OFF_GO] = 0u;
  // zero h_buf[0]: member 0 of each group covers its batch columns (agent scope)
  if (mi == 0) {
    unsigned long long* hbu = (unsigned long long*)p.h_buf;
    for (int i = tid; i < HF * BC / 2; i += NTHR) {
      const int k = i >> 3;
      __hip_atomic_store(&hbu[k * (BATCH / 2) + b0 / 2 + (i & 7)], 0ull,
                         __ATOMIC_RELAXED, __HIP_MEMORY_SCOPE_AGENT);
    }
  }
  post_arrive(p.flags, gi, mi, 1u);
  unsigned bstep = 1;
  int cur = 0;

  const int lane = tid & 63;
  const int bq = tid >> 6;         // wave id = batch quad
  const int kh = lane & 7;         // split-K slice (in-wave reducible)
  const int j  = lane >> 3;        // h feature within tile

  for (int tc0 = 0; tc0 < SEQN; tc0 += TCH) {
    // ================= phase A: input projections for 8 steps ==========
    // x -> LDS [k=128][bt=128], bt swizzled by ((k>>2)&7)<<2 (conflict-free reads)
    {
      float4 xr[16];
#pragma unroll
      for (int it = 0; it < 16; ++it) {
        const int ri = it * 8 + (tid >> 5);           // row = b*8+t
        const int k0 = (tid & 31) * 4;
        xr[it] = *(const float4*)&p.x[((size_t)(b0 + (ri >> 3)) * SEQN + (tc0 + (ri & 7))) * XF + k0];
      }
#pragma unroll
      for (int it = 0; it < 16; ++it) {
        const int ri = it * 8 + (tid >> 5);
        const int k0 = (tid & 31) * 4;
        const float xb[4] = {xr[it].x, xr[it].y, xr[it].z, xr[it].w};
#pragma unroll
        for (int u = 0; u < 4; ++u) {
          const int k = k0 + u;
          sm[OFF_X + k * 128 + (ri ^ (((k >> 2) & 7) << 2))] = xb[u];
        }
      }
      if (tid < 128)   // TV[b*8+t]
        sm[OFF_TV + tid] = p.t[(size_t)(b0 + (tid >> 3)) * SEQN + tc0 + (tid & 7)];
    }
    __syncthreads();
    {
      // thread (c = col-tile of 4 bt, r = j): 6 gates x 4 cols, k = 0..127
      const int c = tid >> 3, r = tid & 7;
      const int c4 = c << 2;
      float a0[4], a1[4], a2[4], a3[4], a4[4], a5[4];
#pragma unroll
      for (int u = 0; u < 4; ++u) { a0[u]=0.f; a1[u]=0.f; a2[u]=0.f; a3[u]=0.f; a4[u]=0.f; a5[u]=0.f; }
      const float* wxp = &sm[OFF_WX + r * 6];
#pragma unroll 4
      for (int k = 0; k < XF; ++k) {
        const float4 xv = *(const float4*)&sm[OFF_X + k * 128 + (c4 ^ (((k >> 2) & 7) << 2))];
        const float2 wA = *(const float2*)&wxp[k * 48 + 0];
        const float2 wB = *(const float2*)&wxp[k * 48 + 2];
        const float2 wC = *(const float2*)&wxp[k * 48 + 4];
        const float xs[4] = {xv.x, xv.y, xv.z, xv.w};
#pragma unroll
        for (int u = 0; u < 4; ++u) {
          a0[u] += wA.x * xs[u]; a1[u] += wA.y * xs[u];
          a2[u] += wB.x * xs[u]; a3[u] += wB.y * xs[u];
          a4[u] += wC.x * xs[u]; a5[u] += wC.y * xs[u];
        }
      }
      const float cfg  = sm[OFF_COEF + 0 * 8 + r], cig  = sm[OFF_COEF + 1 * 8 + r];
      const float cin  = sm[OFF_COEF + 2 * 8 + r];
      const float cogb = sm[OFF_COEF + 3 * 8 + r], cogwt = sm[OFF_COEF + 4 * 8 + r];
      const float ct1w = sm[OFF_COEF + 5 * 8 + r], ct1b = sm[OFF_COEF + 6 * 8 + r];
      const float ct2w = sm[OFF_COEF + 7 * 8 + r], ct2b = sm[OFF_COEF + 8 * 8 + r];
#pragma unroll
      for (int u = 0; u < 4; ++u) {
        const int bt = c4 + u, b = bt >> 3, t = bt & 7;
        const float tv = sm[OFF_TV + bt];
        float* gp = &sm[OFF_G + t * 768 + b * 8 + r];   // [t][g][b*8+j]
        gp[0]   = a0[u] + cfg;
        gp[128] = a1[u] + cig;
        gp[256] = a2[u] + cin;
        gp[384] = a3[u] + cogwt * tv + cogb;
        gp[512] = sigmoidf_(a4[u] + tanhf(ct1w * tv) + ct1b);
        gp[640] = sigmoidf_(a5[u] + tanhf(ct2w * tv) + ct2b);
      }
    }
    __syncthreads();

    // ================= phase B: 8 recurrent steps =================
    for (int tt = 0; tt < TCH; ++tt) {
      wave_wait(sm, p.flags, gi, mi, bstep);
      // stage h tile [k=256][b=16], b swizzled by ((k>>5)&3)<<2
      {
        const unsigned long long* hsrc =
            (const unsigned long long*)(p.h_buf + (size_t)cur * HF * BATCH);
        unsigned long long uv[8];
#pragma unroll
        for (int it = 0; it < 8; ++it) {
          const int i = it * 256 + tid;
          const int k = i >> 3;
          uv[it] = __hip_atomic_load(&hsrc[k * (BATCH / 2) + b0 / 2 + (i & 7)],
                                     __ATOMIC_RELAXED, __HIP_MEMORY_SCOPE_AGENT);
        }
#pragma unroll
        for (int it = 0; it < 8; ++it) {
          const int i = it * 256 + tid;
          const int k = i >> 3, pr = i & 7;
          union { unsigned long long u; float2 f; } cv;
          cv.u = uv[it];
          *(float2*)&sm[OFF_X + k * 16 + ((pr * 2) ^ (((k >> 5) & 3) << 2))] = cv.f;
        }
      }
      __syncthreads();

      // matmul: thread (bq, j, kh): acc[bi][g] over k = kh*32..+31
      float acc[4][4];
#pragma unroll
      for (int bi = 0; bi < 4; ++bi)
#pragma unroll
        for (int g = 0; g < 4; ++g) acc[bi][g] = 0.f;

      const float* hp = &sm[OFF_X + kh * 512 + ((bq ^ (kh & 3)) << 2)];
      const float* wp = &sm[OFF_W + kh * 1024 + (j << 2)];
#pragma unroll 8
      for (int kk = 0; kk < 32; ++kk) {
        const float4 hv = *(const float4*)&hp[kk * 16];   // h[k][bq*4..+3]
        const float4 wv = *(const float4*)&wp[kk * 32];   // w[k][j][0..3]
        acc[0][0] += hv.x * wv.x; acc[0][1] += hv.x * wv.y; acc[0][2] += hv.x * wv.z; acc[0][3] += hv.x * wv.w;
        acc[1][0] += hv.y * wv.x; acc[1][1] += hv.y * wv.y; acc[1][2] += hv.y * wv.z; acc[1][3] += hv.y * wv.w;
        acc[2][0] += hv.z * wv.x; acc[2][1] += hv.z * wv.y; acc[2][2] += hv.z * wv.z; acc[2][3] += hv.z * wv.w;
        acc[3][0] += hv.w * wv.x; acc[3][1] += hv.w * wv.y; acc[3][2] += hv.w * wv.z; acc[3][3] += hv.w * wv.w;
      }

      // in-wave reduce-scatter over kh (3 rounds, 16 swizzles): lane ends with
      // pre[g] = full dot for b = bq*4 + (kh&3)   (kh>=4 duplicates kh-4)
      const int kb0 = kh & 1, kb1 = (kh >> 1) & 1;
      float s1[2][4];
#pragma unroll
      for (int pp = 0; pp < 2; ++pp)
#pragma unroll
        for (int g = 0; g < 4; ++g) {
          const float mine  = kb0 ? acc[2 * pp + 1][g] : acc[2 * pp][g];
          const float yours = kb0 ? acc[2 * pp][g]     : acc[2 * pp + 1][g];
          s1[pp][g] = mine + swzx1(yours);
        }
      float s2[4];
#pragma unroll
      for (int g = 0; g < 4; ++g) {
        const float mine  = kb1 ? s1[1][g] : s1[0][g];
        const float yours = kb1 ? s1[0][g] : s1[1][g];
        s2[g] = mine + swzx2(yours);
      }
      float pre[4];
#pragma unroll
      for (int g = 0; g < 4; ++g) pre[g] = s2[g] + swzx4(s2[g]);

      // gates (all 64 lanes; kh>=4 redundant with kh-4, only kh<4 stores)
      {
        const int bi = kh & 3;
        const int b  = (bq << 2) + bi;
        const int ib = b * 8 + j;
        const float cm = sm[OFF_CM + ib];
        const float* gt = &sm[OFF_G + tt * 768 + ib];
        const float fgx = gt[0],   igx = gt[128], inx = gt[256];
        const float ogx = gt[384], tm1 = gt[512], tm2 = gt[640];
        const float igv = sigmoidf_(sm[OFF_COEF + 10 * 8 + j] * cm + pre[1] + igx);
        const float fgv = sigmoidf_(sm[OFF_COEF + 9 * 8 + j] * cm + pre[0] + fgx);
        const float inn = tanhf(pre[2] + inx);
        const float cbase = fgv * cm, cinn = igv * inn;
        const float cmh = cbase + cinn * tm1;
        const float cmn = cbase + cinn * tm2;
        const float ogv = sigmoidf_(sm[OFF_COEF + 11 * 8 + j] * cmh + pre[3] + ogx);
        const float hn  = ogv * tanhf(cmh);
        const float hn2 = swzx1(hn);                 // partner (b+1) value
        if (kh < 4) {
          sm[OFF_CM + ib] = cmn;
          if (!(kh & 1)) {                           // paired 8B agent-scope h store
            union { float2 f; unsigned long long u; } cv;
            cv.f.x = hn; cv.f.y = hn2;
            unsigned long long* hdst =
                (unsigned long long*)(p.h_buf + (size_t)(cur ^ 1) * HF * BATCH +
                                      (size_t)(h0 + j) * BATCH + b0 + b);
            __hip_atomic_store(hdst, cv.u, __ATOMIC_RELAXED, __HIP_MEMORY_SCOPE_AGENT);
          }
          if (tc0 + tt == SEQN - 1) {
            p.out[(size_t)(b0 + b) * HF + h0 + j] = hn;
            p.out[(size_t)BATCH * HF + (size_t)(b0 + b) * HF + h0 + j] = cmn;
          }
        }
      }
      post_arrive(p.flags, gi, mi, bstep + 1);
      ++bstep;
      cur ^= 1;
    }
  }
}

extern "C" void kernel_launch(void* const* d_in, const int* in_sizes, int n_in,
                              void* d_out, int out_size, void* d_ws, size_t ws_size,
                              hipStream_t stream) {
  (void)in_sizes; (void)n_in; (void)out_size; (void)ws_size;
  Params p;
  p.x = (const float*)d_in[0];
  p.t = (const float*)d_in[1];
  p.w_h[0] = (const float*)d_in[3];   // fg_w_h
  p.w_h[1] = (const float*)d_in[7];   // ig_w_h
  p.w_h[2] = (const float*)d_in[10];  // in_w_h
  p.w_h[3] = (const float*)d_in[14];  // og_w_h
  p.w_x[0] = (const float*)d_in[4];   // fg_w_x
  p.w_x[1] = (const float*)d_in[8];   // ig_w_x
  p.w_x[2] = (const float*)d_in[11];  // in_w_x
  p.w_x[3] = (const float*)d_in[15];  // og_w_x
  p.w_x[4] = (const float*)d_in[18];  // tg1_w_x
  p.w_x[5] = (const float*)d_in[21];  // tg2_w_x
  p.coef[0]  = (const float*)d_in[5];   // fg_b
  p.coef[1]  = (const float*)d_in[9];   // ig_b
  p.coef[2]  = (const float*)d_in[12];  // in_b
  p.coef[3]  = (const float*)d_in[16];  // og_b
  p.coef[4]  = (const float*)d_in[17];  // og_w_t
  p.coef[5]  = (const float*)d_in[19];  // tg1_w_t
  p.coef[6]  = (const float*)d_in[20];  // tg1_b
  p.coef[7]  = (const float*)d_in[22];  // tg2_w_t
  p.coef[8]  = (const float*)d_in[23];  // tg2_b
  p.coef[9]  = (const float*)d_in[2];   // fg_w_c
  p.coef[10] = (const float*)d_in[6];   // ig_w_c
  p.coef[11] = (const float*)d_in[13];  // og_w_cn
  p.flags = (unsigned*)d_ws;                        // [8][32][16] u32 = 16 KiB
  p.h_buf = (float*)((char*)d_ws + 32768);          // [2][H][B] f32 = 256 KiB
  p.out = (float*)d_out;

  hipMemsetAsync(d_ws, 0, 16384, stream);  // arrival flags = 0 each call
  hipFuncSetAttribute((const void*)timelstm_kernel,
                      hipFuncAttributeMaxDynamicSharedMemorySize, LDS_BYTES);
  timelstm_kernel<<<dim3(NBLK), dim3(NTHR), LDS_BYTES, stream>>>(p);
}